// Round 14
// baseline (754.561 us; speedup 1.0000x reference)
//
#include <hip/hip_runtime.h>
#include <stdint.h>

#define D 128
#define CAP 64      // max in-degree bucket (Poisson(16); P(>64) ~ 1e-19)
#define HB 128      // edge-partition slices; per-slice-per-node count < 16 (u4 safe)
#define CH 25000    // node-chunk for hist/fill LDS u4 bins (3125 uints)

typedef __attribute__((ext_vector_type(8))) short bf16x8;
typedef __attribute__((ext_vector_type(4))) float f32x4;

__device__ inline unsigned short f2bf(float x) {
  union { float f; uint32_t u; } v; v.f = x;
  uint32_t u = v.u;
  u += 0x7fffu + ((u >> 16) & 1u);   // RNE
  return (unsigned short)(u >> 16);
}
__device__ inline float bflo(uint32_t u) {
  union { uint32_t u; float f; } v; v.u = u << 16; return v.f;
}
__device__ inline float bfhi(uint32_t u) {
  union { uint32_t u; float f; } v; v.u = u & 0xffff0000u; return v.f;
}
__device__ inline uint32_t packbf(float lo, float hi) {
  return (uint32_t)f2bf(lo) | ((uint32_t)f2bf(hi) << 16);
}

// ---- dual u4 histogram: block = (slice b, chunk c); tail: Wt transpose + zeroing ----
__global__ __launch_bounds__(256) void hist_kernel(
    const int* __restrict__ src, const int* __restrict__ dst,
    unsigned int* __restrict__ parts_s, unsigned int* __restrict__ parts_d,
    int E, int N,
    const float* __restrict__ W0, const float* __restrict__ W1,
    const float* __restrict__ W2, unsigned short* __restrict__ Wt,
    int* __restrict__ cnt, int G, float* __restrict__ outz, int out_total) {
  __shared__ unsigned int lbs[CH / 8];
  __shared__ unsigned int lbd[CH / 8];
  int b = blockIdx.x & (HB - 1);
  int lo = (blockIdx.x >> 7) * CH;
  for (int i = threadIdx.x; i < CH / 8; i += 256) { lbs[i] = 0; lbd[i] = 0; }
  __syncthreads();
  int per = (E + HB - 1) / HB;
  int e0 = b * per;
  int e1 = min(e0 + per, E);
  for (int e = e0 + threadIdx.x; e < e1; e += 256) {
    int rs = src[e] - lo;
    if ((unsigned)rs < CH) atomicAdd(&lbs[rs >> 3], 1u << ((rs & 7) * 4));
    int rd = dst[e] - lo;
    if ((unsigned)rd < CH) atomicAdd(&lbd[rd >> 3], 1u << ((rd & 7) * 4));
  }
  __syncthreads();
  int nu = (N + 7) / 8;
  int base = lo >> 3;
  int cu = min(CH / 8, nu - base);
  unsigned int* ps = parts_s + (size_t)b * nu + base;
  unsigned int* pd = parts_d + (size_t)b * nu + base;
  for (int i = threadIdx.x; i < cu; i += 256) { ps[i] = lbs[i]; pd[i] = lbd[i]; }

  // tail: Wt[l][n][k] = bf16(W_l[k][n]); zero cnt/out (grid-stride, tiny)
  int gs = gridDim.x * 256;
  for (int i = blockIdx.x * 256 + threadIdx.x; i < 3 * 16384; i += gs) {
    int l = i >> 14, r = i & 16383;
    int n = r >> 7, k = r & 127;
    const float* W = (l == 0) ? W0 : (l == 1) ? W1 : W2;
    Wt[i] = f2bf(W[k * 128 + n]);
  }
  for (int i = blockIdx.x * 256 + threadIdx.x; i < G; i += gs) cnt[i] = 0;
  for (int i = blockIdx.x * 256 + threadIdx.x; i < out_total; i += gs) outz[i] = 0.f;
}

// ---- scan over dst u4 partials -> per-slice u8 base offsets + totals + norms ----
// tail: per-graph node counts (for pooling mean)
__global__ void scan_norm_kernel(const unsigned char* __restrict__ parts_s,
                                 const unsigned char* __restrict__ parts_d,
                                 unsigned char* __restrict__ offs_d,
                                 int* __restrict__ degd,
                                 float* __restrict__ cs, float* __restrict__ cd,
                                 const int* __restrict__ gid, int* __restrict__ cnt,
                                 int N) {
  int t = blockIdx.x * blockDim.x + threadIdx.x;
  int i0 = t * 2;
  if (i0 >= N) return;
  int nb = N / 2;  // bytes per slice (N even)
  int ds0 = 0, ds1 = 0, dd0 = 0, dd1 = 0;
  for (int b = 0; b < HB; b++) {
    unsigned char sv = parts_s[(size_t)b * nb + t];
    ds0 += sv & 15; ds1 += sv >> 4;
    unsigned char dv = parts_d[(size_t)b * nb + t];
    offs_d[(size_t)b * N + i0]     = (unsigned char)min(dd0, 255);
    offs_d[(size_t)b * N + i0 + 1] = (unsigned char)min(dd1, 255);
    dd0 += dv & 15; dd1 += dv >> 4;
  }
  degd[i0] = dd0;     degd[i0 + 1] = dd1;
  cs[i0] = rsqrtf((float)ds0 + 1.0f);
  cs[i0 + 1] = rsqrtf((float)ds1 + 1.0f);
  cd[i0] = rsqrtf((float)dd0 + 1.0f);
  cd[i0 + 1] = rsqrtf((float)dd1 + 1.0f);
  atomicAdd(&cnt[gid[i0]], 1);
  if (i0 + 1 < N) atomicAdd(&cnt[gid[i0 + 1]], 1);
}

// ---- CSR fill: block = (slice b, chunk c); u4 LDS cursors; tail: xs = bf16(x*cs) ----
__global__ __launch_bounds__(256) void fill_kernel(
    const int* __restrict__ src, const int* __restrict__ dst,
    const unsigned char* __restrict__ offs_d, int* __restrict__ col, int E, int N,
    const float* __restrict__ x, const float* __restrict__ cs,
    uint32_t* __restrict__ xs) {
  __shared__ unsigned int lcur[CH / 8];
  int b = blockIdx.x & (HB - 1);
  int lo = (blockIdx.x >> 7) * CH;
  for (int i = threadIdx.x; i < CH / 8; i += 256) lcur[i] = 0;
  __syncthreads();
  int per = (E + HB - 1) / HB;
  int e0 = b * per;
  int e1 = min(e0 + per, E);
  const unsigned char* offb = offs_d + (size_t)b * N;
  for (int e = e0 + threadIdx.x; e < e1; e += 256) {
    int d = dst[e];
    int rd = d - lo;
    if ((unsigned)rd < CH) {
      unsigned old = atomicAdd(&lcur[rd >> 3], 1u << ((rd & 7) * 4));
      int local = (old >> ((rd & 7) * 4)) & 0xF;
      int pos = (int)offb[d] + local;
      if (pos < CAP) col[(size_t)d * CAP + pos] = src[e];
    }
  }
  // tail: xs = bf16(x * cs[row]) (grid-stride over float2 groups)
  int total2 = N * 64;
  int gs = gridDim.x * 256;
  for (int i = blockIdx.x * 256 + threadIdx.x; i < total2; i += gs) {
    float2 v = ((const float2*)x)[i];
    float c = cs[i >> 6];
    xs[i] = packbf(v.x * c, v.y * c);
  }
}

// ---- fused layer v2 (R12 measured-best): 512 threads = 8 waves; wave gathers
// nodes 2w,2w+1 and owns column-tile t=w (B-frags in VGPRs; no W LDS tile).
// hout[r] = bf16(relu(((sum_in hs + self) * cd) @ W + b) * rowscale[r])
__global__ __launch_bounds__(512) void fused_layer_kernel(
    const uint32_t* __restrict__ hin, const unsigned short* __restrict__ Wt,
    const float* __restrict__ bias, const float* __restrict__ cd,
    const float* __restrict__ rowscale, const int* __restrict__ degd,
    const int* __restrict__ col, unsigned short* __restrict__ hout, int N) {
  __shared__ __align__(16) uint32_t At[16 * 68];  // 16 rows x 272B (2-way banks = free)

  int wv = threadIdx.x >> 6;   // 0..7
  int lane = threadIdx.x & 63;
  int m = lane & 15;
  int quad = lane >> 4;

  // preload B-fragments for column tile t=wv
  bf16x8 bfr[4];
#pragma unroll
  for (int c = 0; c < 4; c++)
    bfr[c] = *(const bf16x8*)(Wt + (size_t)(16 * wv + m) * 128 + c * 32 + quad * 8);

  // gather phase: 2 nodes per wave
#pragma unroll
  for (int j = 0; j < 2; j++) {
    int w = __builtin_amdgcn_readfirstlane(blockIdx.x * 16 + wv * 2 + j);
    float accx = 0.f, accy = 0.f;
    if (w < N) {
      int n = min(degd[w], CAP);
      const int* cw = col + (size_t)w * CAP;
      const uint32_t* hl = hin + lane;
      uint32_t selfv = hl[(size_t)w * 64];
      accx = bflo(selfv); accy = bfhi(selfv);
      int i = 0;
      for (; i + 7 < n; i += 8) {
        int s0 = cw[i],     s1 = cw[i + 1], s2 = cw[i + 2], s3 = cw[i + 3];
        int s4 = cw[i + 4], s5 = cw[i + 5], s6 = cw[i + 6], s7 = cw[i + 7];
        uint32_t v0 = hl[(size_t)s0 * 64];
        uint32_t v1 = hl[(size_t)s1 * 64];
        uint32_t v2 = hl[(size_t)s2 * 64];
        uint32_t v3 = hl[(size_t)s3 * 64];
        uint32_t v4 = hl[(size_t)s4 * 64];
        uint32_t v5 = hl[(size_t)s5 * 64];
        uint32_t v6 = hl[(size_t)s6 * 64];
        uint32_t v7 = hl[(size_t)s7 * 64];
        accx += bflo(v0); accy += bfhi(v0);
        accx += bflo(v1); accy += bfhi(v1);
        accx += bflo(v2); accy += bfhi(v2);
        accx += bflo(v3); accy += bfhi(v3);
        accx += bflo(v4); accy += bfhi(v4);
        accx += bflo(v5); accy += bfhi(v5);
        accx += bflo(v6); accy += bfhi(v6);
        accx += bflo(v7); accy += bfhi(v7);
      }
      for (; i + 3 < n; i += 4) {
        int s0 = cw[i], s1 = cw[i + 1], s2 = cw[i + 2], s3 = cw[i + 3];
        uint32_t v0 = hl[(size_t)s0 * 64];
        uint32_t v1 = hl[(size_t)s1 * 64];
        uint32_t v2 = hl[(size_t)s2 * 64];
        uint32_t v3 = hl[(size_t)s3 * 64];
        accx += bflo(v0); accy += bfhi(v0);
        accx += bflo(v1); accy += bfhi(v1);
        accx += bflo(v2); accy += bfhi(v2);
        accx += bflo(v3); accy += bfhi(v3);
      }
      for (; i < n; i++) {
        uint32_t v = hl[(size_t)cw[i] * 64];
        accx += bflo(v); accy += bfhi(v);
      }
      float cdv = cd[w];
      accx *= cdv; accy *= cdv;
    }
    At[(wv * 2 + j) * 68 + lane] = packbf(accx, accy);
  }
  __syncthreads();

  // MFMA phase: wave wv computes 16 rows x cols [16*wv .. 16*wv+15], K=128
  const unsigned short* arow = (const unsigned short*)At + m * 136;
  f32x4 acc = f32x4{0.f, 0.f, 0.f, 0.f};
#pragma unroll
  for (int c = 0; c < 4; c++) {
    bf16x8 a = *(const bf16x8*)(arow + c * 32 + quad * 8);  // A[m][k]
    acc = __builtin_amdgcn_mfma_f32_16x16x32_bf16(a, bfr[c], acc, 0, 0, 0);
  }
  // C/D: col = lane&15 (-> 16*wv+m), row = quad*4 + i
  int colb = 16 * wv + m;
  float bv = bias[colb];
#pragma unroll
  for (int i = 0; i < 4; i++) {
    int r = blockIdx.x * 16 + quad * 4 + i;
    if (r < N) {
      float v = acc[i] + bv;
      v = v > 0.f ? v : 0.f;
      if (rowscale) v *= rowscale[r];
      hout[(size_t)r * D + colb] = f2bf(v);
    }
  }
}

// ---- segment-mean pooling: applies 1/cnt before atomic (no div kernel) ----
__global__ void pool_kernel(const unsigned short* __restrict__ h, const int* __restrict__ gid,
                            float* __restrict__ outsum, const int* __restrict__ cnt, int N) {
  int v0 = blockIdx.x * 64;
  if (v0 >= N) return;
  int d = threadIdx.x;
  int vend = min(v0 + 64, N);
  int cur = gid[v0];
  float acc = 0.f;
  for (int v = v0; v < vend; v++) {
    int g = gid[v];
    if (g != cur) {
      float inv = 1.0f / fmaxf((float)cnt[cur], 1.0f);
      atomicAdd(&outsum[cur * D + d], acc * inv);
      acc = 0.f; cur = g;
    }
    unsigned short hv = __builtin_nontemporal_load(&h[(size_t)v * D + d]);
    union { uint32_t u; float f; } cv; cv.u = (uint32_t)hv << 16;
    acc += cv.f;
  }
  float inv = 1.0f / fmaxf((float)cnt[cur], 1.0f);
  atomicAdd(&outsum[cur * D + d], acc * inv);
}

extern "C" void kernel_launch(void* const* d_in, const int* in_sizes, int n_in,
                              void* d_out, int out_size, void* d_ws, size_t ws_size,
                              hipStream_t stream) {
  const float* x  = (const float*)d_in[0];
  const float* W0 = (const float*)d_in[1];
  const float* b0 = (const float*)d_in[2];
  const float* W1 = (const float*)d_in[3];
  const float* b1 = (const float*)d_in[4];
  const float* W2 = (const float*)d_in[5];
  const float* b2 = (const float*)d_in[6];
  const int* src  = (const int*)d_in[7];
  const int* dst  = (const int*)d_in[8];
  const int* gid  = (const int*)d_in[9];

  const int N = in_sizes[0] / D;
  const int E = in_sizes[7];
  const int G = out_size / D;
  const int nu = (N + 7) / 8;  // uints per u4-histogram slice

  // workspace layout
  uint32_t* hsA = (uint32_t*)d_ws;                     // N*64 (bf16x2)  25.6 MB
  uint32_t* hsB = hsA + (size_t)N * 64;                // N*64           25.6 MB
  int* col      = (int*)(hsB + (size_t)N * 64);        // N*CAP          25.6 MB
  int* degd     = col + (size_t)N * CAP;               // N
  float* csb    = (float*)(degd + N);                  // N
  float* cdb    = csb + N;                             // N
  int* cnt      = (int*)(cdb + N);                     // G
  unsigned short* Wt = (unsigned short*)(cnt + G);     // 3*16384
  unsigned int* parts_s = (unsigned int*)(Wt + 3 * 16384);   // HB*nu uints (6.4 MB)
  unsigned int* parts_d = parts_s + (size_t)HB * nu;         // HB*nu uints (6.4 MB)
  unsigned char* offs_d = (unsigned char*)(parts_d + (size_t)HB * nu);  // HB*N (12.8 MB)

  const int nch = (N + CH - 1) / CH;
  hist_kernel<<<HB * nch, 256, 0, stream>>>(src, dst, parts_s, parts_d, E, N,
                                            W0, W1, W2, Wt, cnt, G,
                                            (float*)d_out, out_size);
  scan_norm_kernel<<<(N / 2 + 255) / 256, 256, 0, stream>>>(
      (const unsigned char*)parts_s, (const unsigned char*)parts_d, offs_d,
      degd, csb, cdb, gid, cnt, N);
  fill_kernel<<<HB * nch, 256, 0, stream>>>(src, dst, offs_d, col, E, N, x, csb, hsA);

  const int ltiles = (N + 15) / 16;  // 16 nodes per fused block

  // ping-pong: A -> B -> A -> B
  fused_layer_kernel<<<ltiles, 512, 0, stream>>>(hsA, Wt, b0, cdb, csb, degd, col,
                                                 (unsigned short*)hsB, N);
  fused_layer_kernel<<<ltiles, 512, 0, stream>>>(hsB, Wt + 16384, b1, cdb, csb, degd, col,
                                                 (unsigned short*)hsA, N);
  fused_layer_kernel<<<ltiles, 512, 0, stream>>>(hsA, Wt + 2 * 16384, b2, cdb, nullptr, degd, col,
                                                 (unsigned short*)hsB, N);

  pool_kernel<<<(N + 63) / 64, 128, 0, stream>>>((const unsigned short*)hsB, gid,
                                                 (float*)d_out, cnt, N);
}

// Round 15
// 458.055 us; speedup vs baseline: 1.6473x; 1.6473x over previous
//
#include <hip/hip_runtime.h>
#include <stdint.h>

#define D 128
#define CAP 64      // max in-degree bucket (Poisson(16); P(>64) ~ 1e-19)
#define HB 128      // edge-partition slices; per-slice-per-node count < 16 (u4 safe)
#define CH 25000    // node-chunk for hist/fill LDS u4 bins (3125 uints)

typedef __attribute__((ext_vector_type(8))) short bf16x8;
typedef __attribute__((ext_vector_type(4))) float f32x4;

__device__ inline unsigned short f2bf(float x) {
  union { float f; uint32_t u; } v; v.f = x;
  uint32_t u = v.u;
  u += 0x7fffu + ((u >> 16) & 1u);   // RNE
  return (unsigned short)(u >> 16);
}
__device__ inline float bflo(uint32_t u) {
  union { uint32_t u; float f; } v; v.u = u << 16; return v.f;
}
__device__ inline float bfhi(uint32_t u) {
  union { uint32_t u; float f; } v; v.u = u & 0xffff0000u; return v.f;
}
__device__ inline uint32_t packbf(float lo, float hi) {
  return (uint32_t)f2bf(lo) | ((uint32_t)f2bf(hi) << 16);
}

// ---- dual u4 histogram: block = (slice b, chunk c); tail: Wt transpose + zeroing ----
__global__ __launch_bounds__(256) void hist_kernel(
    const int* __restrict__ src, const int* __restrict__ dst,
    unsigned int* __restrict__ parts_s, unsigned int* __restrict__ parts_d,
    int E, int N,
    const float* __restrict__ W0, const float* __restrict__ W1,
    const float* __restrict__ W2, unsigned short* __restrict__ Wt,
    int* __restrict__ cnt, int G, float* __restrict__ outz, int out_total) {
  __shared__ unsigned int lbs[CH / 8];
  __shared__ unsigned int lbd[CH / 8];
  int b = blockIdx.x & (HB - 1);
  int lo = (blockIdx.x >> 7) * CH;
  for (int i = threadIdx.x; i < CH / 8; i += 256) { lbs[i] = 0; lbd[i] = 0; }
  __syncthreads();
  int per = (E + HB - 1) / HB;
  int e0 = b * per;
  int e1 = min(e0 + per, E);
  for (int e = e0 + threadIdx.x; e < e1; e += 256) {
    int rs = src[e] - lo;
    if ((unsigned)rs < CH) atomicAdd(&lbs[rs >> 3], 1u << ((rs & 7) * 4));
    int rd = dst[e] - lo;
    if ((unsigned)rd < CH) atomicAdd(&lbd[rd >> 3], 1u << ((rd & 7) * 4));
  }
  __syncthreads();
  int nu = (N + 7) / 8;
  int base = lo >> 3;
  int cu = min(CH / 8, nu - base);
  unsigned int* ps = parts_s + (size_t)b * nu + base;
  unsigned int* pd = parts_d + (size_t)b * nu + base;
  for (int i = threadIdx.x; i < cu; i += 256) { ps[i] = lbs[i]; pd[i] = lbd[i]; }

  // tail: Wt[l][n][k] = bf16(W_l[k][n]); zero cnt/out (grid-stride, tiny)
  int gs = gridDim.x * 256;
  for (int i = blockIdx.x * 256 + threadIdx.x; i < 3 * 16384; i += gs) {
    int l = i >> 14, r = i & 16383;
    int n = r >> 7, k = r & 127;
    const float* W = (l == 0) ? W0 : (l == 1) ? W1 : W2;
    Wt[i] = f2bf(W[k * 128 + n]);
  }
  for (int i = blockIdx.x * 256 + threadIdx.x; i < G; i += gs) cnt[i] = 0;
  for (int i = blockIdx.x * 256 + threadIdx.x; i < out_total; i += gs) outz[i] = 0.f;
}

// ---- scan over dst u4 partials -> per-slice u8 base offsets + totals + norms ----
// tail: per-graph node counts via per-block LDS histogram (few global atomics)
__global__ __launch_bounds__(256) void scan_norm_kernel(
    const unsigned char* __restrict__ parts_s,
    const unsigned char* __restrict__ parts_d,
    unsigned char* __restrict__ offs_d,
    int* __restrict__ degd,
    float* __restrict__ cs, float* __restrict__ cd,
    const int* __restrict__ gid, int* __restrict__ cnt,
    int N, int G) {
  __shared__ int lcnt[256];  // G <= 256 bins
  for (int i = threadIdx.x; i < G; i += 256) lcnt[i] = 0;
  __syncthreads();

  int t = blockIdx.x * blockDim.x + threadIdx.x;
  int i0 = t * 2;
  if (i0 < N) {
    int nb = N / 2;  // bytes per slice (N even)
    int ds0 = 0, ds1 = 0, dd0 = 0, dd1 = 0;
    for (int b = 0; b < HB; b++) {
      unsigned char sv = parts_s[(size_t)b * nb + t];
      ds0 += sv & 15; ds1 += sv >> 4;
      unsigned char dv = parts_d[(size_t)b * nb + t];
      offs_d[(size_t)b * N + i0]     = (unsigned char)min(dd0, 255);
      offs_d[(size_t)b * N + i0 + 1] = (unsigned char)min(dd1, 255);
      dd0 += dv & 15; dd1 += dv >> 4;
    }
    degd[i0] = dd0;     degd[i0 + 1] = dd1;
    cs[i0] = rsqrtf((float)ds0 + 1.0f);
    cs[i0 + 1] = rsqrtf((float)ds1 + 1.0f);
    cd[i0] = rsqrtf((float)dd0 + 1.0f);
    cd[i0 + 1] = rsqrtf((float)dd1 + 1.0f);
    atomicAdd(&lcnt[gid[i0]], 1);
    if (i0 + 1 < N) atomicAdd(&lcnt[gid[i0 + 1]], 1);
  }
  __syncthreads();
  for (int i = threadIdx.x; i < G; i += 256) {
    int c = lcnt[i];
    if (c) atomicAdd(&cnt[i], c);
  }
}

// ---- CSR fill: block = (slice b, chunk c); u4 LDS cursors; tail: xs = bf16(x*cs) ----
__global__ __launch_bounds__(256) void fill_kernel(
    const int* __restrict__ src, const int* __restrict__ dst,
    const unsigned char* __restrict__ offs_d, int* __restrict__ col, int E, int N,
    const float* __restrict__ x, const float* __restrict__ cs,
    uint32_t* __restrict__ xs) {
  __shared__ unsigned int lcur[CH / 8];
  int b = blockIdx.x & (HB - 1);
  int lo = (blockIdx.x >> 7) * CH;
  for (int i = threadIdx.x; i < CH / 8; i += 256) lcur[i] = 0;
  __syncthreads();
  int per = (E + HB - 1) / HB;
  int e0 = b * per;
  int e1 = min(e0 + per, E);
  const unsigned char* offb = offs_d + (size_t)b * N;
  for (int e = e0 + threadIdx.x; e < e1; e += 256) {
    int d = dst[e];
    int rd = d - lo;
    if ((unsigned)rd < CH) {
      unsigned old = atomicAdd(&lcur[rd >> 3], 1u << ((rd & 7) * 4));
      int local = (old >> ((rd & 7) * 4)) & 0xF;
      int pos = (int)offb[d] + local;
      if (pos < CAP) col[(size_t)d * CAP + pos] = src[e];
    }
  }
  // tail: xs = bf16(x * cs[row]) (grid-stride over float2 groups)
  int total2 = N * 64;
  int gs = gridDim.x * 256;
  for (int i = blockIdx.x * 256 + threadIdx.x; i < total2; i += gs) {
    float2 v = ((const float2*)x)[i];
    float c = cs[i >> 6];
    xs[i] = packbf(v.x * c, v.y * c);
  }
}

// ---- fused layer v2 (R12 measured-best): 512 threads = 8 waves; wave gathers
// nodes 2w,2w+1 and owns column-tile t=w (B-frags in VGPRs; no W LDS tile).
// hout[r] = bf16(relu(((sum_in hs + self) * cd) @ W + b) * rowscale[r])
__global__ __launch_bounds__(512) void fused_layer_kernel(
    const uint32_t* __restrict__ hin, const unsigned short* __restrict__ Wt,
    const float* __restrict__ bias, const float* __restrict__ cd,
    const float* __restrict__ rowscale, const int* __restrict__ degd,
    const int* __restrict__ col, unsigned short* __restrict__ hout, int N) {
  __shared__ __align__(16) uint32_t At[16 * 68];  // 16 rows x 272B (2-way banks = free)

  int wv = threadIdx.x >> 6;   // 0..7
  int lane = threadIdx.x & 63;
  int m = lane & 15;
  int quad = lane >> 4;

  // preload B-fragments for column tile t=wv
  bf16x8 bfr[4];
#pragma unroll
  for (int c = 0; c < 4; c++)
    bfr[c] = *(const bf16x8*)(Wt + (size_t)(16 * wv + m) * 128 + c * 32 + quad * 8);

  // gather phase: 2 nodes per wave
#pragma unroll
  for (int j = 0; j < 2; j++) {
    int w = __builtin_amdgcn_readfirstlane(blockIdx.x * 16 + wv * 2 + j);
    float accx = 0.f, accy = 0.f;
    if (w < N) {
      int n = min(degd[w], CAP);
      const int* cw = col + (size_t)w * CAP;
      const uint32_t* hl = hin + lane;
      uint32_t selfv = hl[(size_t)w * 64];
      accx = bflo(selfv); accy = bfhi(selfv);
      int i = 0;
      for (; i + 7 < n; i += 8) {
        int s0 = cw[i],     s1 = cw[i + 1], s2 = cw[i + 2], s3 = cw[i + 3];
        int s4 = cw[i + 4], s5 = cw[i + 5], s6 = cw[i + 6], s7 = cw[i + 7];
        uint32_t v0 = hl[(size_t)s0 * 64];
        uint32_t v1 = hl[(size_t)s1 * 64];
        uint32_t v2 = hl[(size_t)s2 * 64];
        uint32_t v3 = hl[(size_t)s3 * 64];
        uint32_t v4 = hl[(size_t)s4 * 64];
        uint32_t v5 = hl[(size_t)s5 * 64];
        uint32_t v6 = hl[(size_t)s6 * 64];
        uint32_t v7 = hl[(size_t)s7 * 64];
        accx += bflo(v0); accy += bfhi(v0);
        accx += bflo(v1); accy += bfhi(v1);
        accx += bflo(v2); accy += bfhi(v2);
        accx += bflo(v3); accy += bfhi(v3);
        accx += bflo(v4); accy += bfhi(v4);
        accx += bflo(v5); accy += bfhi(v5);
        accx += bflo(v6); accy += bfhi(v6);
        accx += bflo(v7); accy += bfhi(v7);
      }
      for (; i + 3 < n; i += 4) {
        int s0 = cw[i], s1 = cw[i + 1], s2 = cw[i + 2], s3 = cw[i + 3];
        uint32_t v0 = hl[(size_t)s0 * 64];
        uint32_t v1 = hl[(size_t)s1 * 64];
        uint32_t v2 = hl[(size_t)s2 * 64];
        uint32_t v3 = hl[(size_t)s3 * 64];
        accx += bflo(v0); accy += bfhi(v0);
        accx += bflo(v1); accy += bfhi(v1);
        accx += bflo(v2); accy += bfhi(v2);
        accx += bflo(v3); accy += bfhi(v3);
      }
      for (; i < n; i++) {
        uint32_t v = hl[(size_t)cw[i] * 64];
        accx += bflo(v); accy += bfhi(v);
      }
      float cdv = cd[w];
      accx *= cdv; accy *= cdv;
    }
    At[(wv * 2 + j) * 68 + lane] = packbf(accx, accy);
  }
  __syncthreads();

  // MFMA phase: wave wv computes 16 rows x cols [16*wv .. 16*wv+15], K=128
  const unsigned short* arow = (const unsigned short*)At + m * 136;
  f32x4 acc = f32x4{0.f, 0.f, 0.f, 0.f};
#pragma unroll
  for (int c = 0; c < 4; c++) {
    bf16x8 a = *(const bf16x8*)(arow + c * 32 + quad * 8);  // A[m][k]
    acc = __builtin_amdgcn_mfma_f32_16x16x32_bf16(a, bfr[c], acc, 0, 0, 0);
  }
  // C/D: col = lane&15 (-> 16*wv+m), row = quad*4 + i
  int colb = 16 * wv + m;
  float bv = bias[colb];
#pragma unroll
  for (int i = 0; i < 4; i++) {
    int r = blockIdx.x * 16 + quad * 4 + i;
    if (r < N) {
      float v = acc[i] + bv;
      v = v > 0.f ? v : 0.f;
      if (rowscale) v *= rowscale[r];
      hout[(size_t)r * D + colb] = f2bf(v);
    }
  }
}

// ---- segment-mean pooling: applies 1/cnt before atomic (no div kernel) ----
__global__ void pool_kernel(const unsigned short* __restrict__ h, const int* __restrict__ gid,
                            float* __restrict__ outsum, const int* __restrict__ cnt, int N) {
  int v0 = blockIdx.x * 64;
  if (v0 >= N) return;
  int d = threadIdx.x;
  int vend = min(v0 + 64, N);
  int cur = gid[v0];
  float acc = 0.f;
  for (int v = v0; v < vend; v++) {
    int g = gid[v];
    if (g != cur) {
      float inv = 1.0f / fmaxf((float)cnt[cur], 1.0f);
      atomicAdd(&outsum[cur * D + d], acc * inv);
      acc = 0.f; cur = g;
    }
    unsigned short hv = __builtin_nontemporal_load(&h[(size_t)v * D + d]);
    union { uint32_t u; float f; } cv; cv.u = (uint32_t)hv << 16;
    acc += cv.f;
  }
  float inv = 1.0f / fmaxf((float)cnt[cur], 1.0f);
  atomicAdd(&outsum[cur * D + d], acc * inv);
}

extern "C" void kernel_launch(void* const* d_in, const int* in_sizes, int n_in,
                              void* d_out, int out_size, void* d_ws, size_t ws_size,
                              hipStream_t stream) {
  const float* x  = (const float*)d_in[0];
  const float* W0 = (const float*)d_in[1];
  const float* b0 = (const float*)d_in[2];
  const float* W1 = (const float*)d_in[3];
  const float* b1 = (const float*)d_in[4];
  const float* W2 = (const float*)d_in[5];
  const float* b2 = (const float*)d_in[6];
  const int* src  = (const int*)d_in[7];
  const int* dst  = (const int*)d_in[8];
  const int* gid  = (const int*)d_in[9];

  const int N = in_sizes[0] / D;
  const int E = in_sizes[7];
  const int G = out_size / D;
  const int nu = (N + 7) / 8;  // uints per u4-histogram slice

  // workspace layout
  uint32_t* hsA = (uint32_t*)d_ws;                     // N*64 (bf16x2)  25.6 MB
  uint32_t* hsB = hsA + (size_t)N * 64;                // N*64           25.6 MB
  int* col      = (int*)(hsB + (size_t)N * 64);        // N*CAP          25.6 MB
  int* degd     = col + (size_t)N * CAP;               // N
  float* csb    = (float*)(degd + N);                  // N
  float* cdb    = csb + N;                             // N
  int* cnt      = (int*)(cdb + N);                     // G
  unsigned short* Wt = (unsigned short*)(cnt + G);     // 3*16384
  unsigned int* parts_s = (unsigned int*)(Wt + 3 * 16384);   // HB*nu uints (6.4 MB)
  unsigned int* parts_d = parts_s + (size_t)HB * nu;         // HB*nu uints (6.4 MB)
  unsigned char* offs_d = (unsigned char*)(parts_d + (size_t)HB * nu);  // HB*N (12.8 MB)

  const int nch = (N + CH - 1) / CH;
  hist_kernel<<<HB * nch, 256, 0, stream>>>(src, dst, parts_s, parts_d, E, N,
                                            W0, W1, W2, Wt, cnt, G,
                                            (float*)d_out, out_size);
  scan_norm_kernel<<<(N / 2 + 255) / 256, 256, 0, stream>>>(
      (const unsigned char*)parts_s, (const unsigned char*)parts_d, offs_d,
      degd, csb, cdb, gid, cnt, N, G);
  fill_kernel<<<HB * nch, 256, 0, stream>>>(src, dst, offs_d, col, E, N, x, csb, hsA);

  const int ltiles = (N + 15) / 16;  // 16 nodes per fused block

  // ping-pong: A -> B -> A -> B
  fused_layer_kernel<<<ltiles, 512, 0, stream>>>(hsA, Wt, b0, cdb, csb, degd, col,
                                                 (unsigned short*)hsB, N);
  fused_layer_kernel<<<ltiles, 512, 0, stream>>>(hsB, Wt + 16384, b1, cdb, csb, degd, col,
                                                 (unsigned short*)hsA, N);
  fused_layer_kernel<<<ltiles, 512, 0, stream>>>(hsA, Wt + 2 * 16384, b2, cdb, nullptr, degd, col,
                                                 (unsigned short*)hsB, N);

  pool_kernel<<<(N + 63) / 64, 128, 0, stream>>>((const unsigned short*)hsB, gid,
                                                 (float*)d_out, cnt, N);
}